// Round 10
// baseline (165.673 us; speedup 1.0000x reference)
//
#include <hip/hip_runtime.h>
#include <math.h>

// Problem constants
#define BS 4
#define LQ 1024
#define EMB 256
#define NH 8
#define NL 4
#define NP 16
#define HD 32
#define LV 5440     // 64*64 + 32*32 + 16*16 + 8*8
#define LVP 5936    // padded: 66^2 + 34^2 + 18^2 + 10^2
#define KDIM 256    // all GEMMs have K = 256

typedef _Float16 half8 __attribute__((ext_vector_type(8)));  // 8 f16 = 4 VGPRs
typedef _Float16 h2    __attribute__((ext_vector_type(2)));  // packed f16 pair
typedef __attribute__((ext_vector_type(4))) float f32x4;

__device__ inline unsigned short f2h(float f) {
    return __builtin_bit_cast(unsigned short, (_Float16)f);   // v_cvt_f16_f32 RNE
}
__device__ inline h2 pk2(float f) {
    return __builtin_bit_cast(h2, __builtin_amdgcn_cvt_pkrtz(f, f));
}

// Fragment-major layout for a row-major [R][256] f16 matrix:
//   offset = ((r>>4)*8 + (k>>5))*512 + ((r&15) + 16*((k>>3)&3))*8 + (k&7)
// A wave's 16x16x32 MFMA fragment load = ONE contiguous 1KB burst
// (global_load_dwordx4 at tile_base + lane*16B).  [R6 lesson]

// ---------------- prep ------------------------------------------------------------
// blocks [0,512):    weights [K=256][N] fp32 -> Wt fragment-major f16 rows:
//                    0..255 W_value | 256..1279 W_off | 1280..1791 W_attn | 1792..2047 W_out
// blocks [512,916):  value/query fp32 -> fragment-major f16; one 16-row group per
//                    wave, lane = fragment slot -> contiguous 1KB stores (R7 had
//                    4x write amplification from strided 16B stores).
// blocks [916,1164): zero the 1-pixel borders of padded v_proj
__global__ __launch_bounds__(256) void prep(const float* __restrict__ Wv,
                                            const float* __restrict__ Wo,
                                            const float* __restrict__ Wa,
                                            const float* __restrict__ Wu,
                                            const float* __restrict__ value,
                                            const float* __restrict__ query,
                                            unsigned short* __restrict__ Wt,
                                            unsigned short* __restrict__ val_h,
                                            unsigned short* __restrict__ qry_h,
                                            unsigned short* __restrict__ v_pad) {
    const int blk = blockIdx.x;
    const int t = threadIdx.x;
    if (blk < 512) {
        __shared__ float tile[32][33];     // [k_local][n_local]
        const int n0 = (blk & 63) * 32, k0 = (blk >> 6) * 32;
        const float* src; int N, nloc;
        if (n0 < 256)       { src = Wv; N = 256;  nloc = n0; }
        else if (n0 < 1280) { src = Wo; N = 1024; nloc = n0 - 256; }
        else if (n0 < 1792) { src = Wa; N = 512;  nloc = n0 - 1280; }
        else                { src = Wu; N = 256;  nloc = n0 - 1792; }
        const int tx = t & 31, ty = t >> 5;  // ty 0..7
#pragma unroll
        for (int i = 0; i < 32; i += 8)
            tile[ty + i][tx] = src[(size_t)(k0 + ty + i) * N + nloc + tx];
        __syncthreads();
        if (t < 128) {                       // 32 n x 4 k-octets
            const int n_loc = t & 31, oct = t >> 5;
            const int n = n0 + n_loc;
            unsigned short h[8];
#pragma unroll
            for (int e = 0; e < 8; ++e) h[e] = f2h(tile[oct * 8 + e][n_loc]);
            const size_t off = ((size_t)(n >> 4) * 8 + (k0 >> 5)) * 512
                             + ((n & 15) + 16 * oct) * 8;
            *(uint4*)(Wt + off) = *(const uint4*)h;
        }
    } else if (blk < 916) {
        const int u = (blk - 512) * 4 + (t >> 6);   // 16-row group id, 0..1615
        const int lane = t & 63;
        const float* src; unsigned short* dst; int rg;
        if (u < 1360) { src = value; dst = val_h; rg = u; }
        else          { src = query; dst = qry_h; rg = u - 1360; }
        const int r = rg * 16 + (lane & 15);
        const int quad = lane >> 4;
        const float* sp = src + (size_t)r * KDIM + quad * 8;
        unsigned short* dp = dst + (size_t)rg * 4096 + lane * 8;
#pragma unroll
        for (int kt = 0; kt < 8; ++kt) {
            const float4 f0 = *(const float4*)(sp + kt * 32);
            const float4 f1 = *(const float4*)(sp + kt * 32 + 4);
            unsigned short h[8];
            h[0] = f2h(f0.x); h[1] = f2h(f0.y); h[2] = f2h(f0.z); h[3] = f2h(f0.w);
            h[4] = f2h(f1.x); h[5] = f2h(f1.y); h[6] = f2h(f1.z); h[7] = f2h(f1.w);
            *(uint4*)(dp + kt * 512) = *(const uint4*)h;   // contiguous 1KB/wave
        }
    } else {
        // zero border pixels of padded v (1984 pixels, 512B each)
        const int pidx = (blk - 916) * 8 + (t >> 5);   // 0..1983
        const int lane32 = t & 31;
        const unsigned b = (unsigned)pidx / 496u;
        const unsigned rem = (unsigned)pidx - b * 496u;
        int Wd, W2, pb, i;
        if (rem < 260)      { Wd = 64; W2 = 66; pb = 0;    i = rem; }
        else if (rem < 392) { Wd = 32; W2 = 34; pb = 4356; i = rem - 260; }
        else if (rem < 460) { Wd = 16; W2 = 18; pb = 5512; i = rem - 392; }
        else                { Wd = 8;  W2 = 10; pb = 5836; i = rem - 460; }
        int y, x;
        if (i < W2)          { y = 0;      x = i; }
        else if (i < 2 * W2) { y = Wd + 1; x = i - W2; }
        else { const int j = i - 2 * W2; y = 1 + (j >> 1); x = (j & 1) ? (Wd + 1) : 0; }
        const size_t off = ((size_t)b * LVP + pb + y * W2 + x) * EMB + lane32 * 8;
        uint4 z = {0, 0, 0, 0};
        *(uint4*)(v_pad + off) = z;
    }
}

// ---------------- barrier-free no-LDS f16 MFMA GEMM, 128x128 tile ----------------
// MODE 0: fp32 row-major C = acc + bias[c]
// MODE 1: fused qkv epilogue (N=1536): cols <1024 -> sampling locations with
//         reference-point polynomial; cols >=1024 -> attn logits + fused softmax.
// MODE 2: f16 v-projection written into the PADDED v layout (row -> b,lvl,y,x).
template <int MODE>
__device__ __forceinline__ void gemm_nolds(const unsigned short* __restrict__ A,
                                           const unsigned short* __restrict__ Bt,
                                           const float* __restrict__ bias,
                                           const float* __restrict__ bias2,
                                           const float* __restrict__ refp,
                                           void* __restrict__ Cv,
                                           float* __restrict__ C2,
                                           int N, int bx, int by) {
    const int t = threadIdx.x;
    const int lane = t & 63, w = t >> 6;
    const int quad = lane >> 4, l16 = lane & 15;
    const int wr = w >> 1, wc = w & 1;
    const int row0 = by * 128, col0 = bx * 128;

    const unsigned short* ap = A  + ((size_t)((row0 >> 4) + wr * 4) * 8) * 512 + lane * 8;
    const unsigned short* bp = Bt + ((size_t)((col0 >> 4) + wc * 4) * 8) * 512 + lane * 8;

    f32x4 acc[4][4] = {};

#pragma unroll 2
    for (int kt = 0; kt < 8; ++kt) {
        half8 af[4], bf[4];
#pragma unroll
        for (int mi = 0; mi < 4; ++mi)
            af[mi] = *(const half8*)(ap + (size_t)mi * 4096 + kt * 512);
#pragma unroll
        for (int ni = 0; ni < 4; ++ni)
            bf[ni] = *(const half8*)(bp + (size_t)ni * 4096 + kt * 512);
#pragma unroll
        for (int mi = 0; mi < 4; ++mi)
#pragma unroll
            for (int ni = 0; ni < 4; ++ni)
                acc[mi][ni] = __builtin_amdgcn_mfma_f32_16x16x32_f16(af[mi], bf[ni],
                                                                     acc[mi][ni], 0, 0, 0);
    }

    // C/D layout: col = lane&15, row = quad*4 + reg (dtype-independent; m89/m121+)
    if (MODE == 0) {
#pragma unroll
        for (int ni = 0; ni < 4; ++ni) {
            const int c = col0 + wc * 64 + ni * 16 + l16;
            const float bv = bias[c];
#pragma unroll
            for (int mi = 0; mi < 4; ++mi) {
                const int r0 = row0 + wr * 64 + mi * 16 + quad * 4;
#pragma unroll
                for (int rr = 0; rr < 4; ++rr)
                    ((float*)Cv)[(size_t)(r0 + rr) * N + c] = acc[mi][ni][rr] + bv;
            }
        }
    } else if (MODE == 2) {
        unsigned short* C = (unsigned short*)Cv;
        float bv[4];
        int cc[4];
#pragma unroll
        for (int ni = 0; ni < 4; ++ni) {
            cc[ni] = col0 + wc * 64 + ni * 16 + l16;
            bv[ni] = bias[cc[ni]];
        }
#pragma unroll
        for (int mi = 0; mi < 4; ++mi) {
#pragma unroll
            for (int rr = 0; rr < 4; ++rr) {
                const unsigned r = row0 + wr * 64 + mi * 16 + quad * 4 + rr;
                const unsigned b = r / 5440u;
                const unsigned flat = r - b * 5440u;
                unsigned y, x, W2, pb;
                if (flat < 4096)      { y = flat >> 6; x = flat & 63; W2 = 66; pb = 0; }
                else if (flat < 5120) { const unsigned f = flat - 4096; y = f >> 5; x = f & 31; W2 = 34; pb = 4356; }
                else if (flat < 5376) { const unsigned f = flat - 5120; y = f >> 4; x = f & 15; W2 = 18; pb = 5512; }
                else                  { const unsigned f = flat - 5376; y = f >> 3; x = f & 7;  W2 = 10; pb = 5836; }
                const size_t rowbase = ((size_t)b * LVP + pb + (y + 1) * W2 + (x + 1)) * EMB;
#pragma unroll
                for (int ni = 0; ni < 4; ++ni)
                    C[rowbase + cc[ni]] = f2h(acc[mi][ni][rr] + bv[ni]);
            }
        }
    } else {
        const bool is_off = (col0 < 1024);   // block-uniform (1024 % 128 == 0)
        if (is_off) {
            float* C = (float*)Cv;
#pragma unroll
            for (int ni = 0; ni < 4; ++ni) {
                const int cg = col0 + wc * 64 + ni * 16 + l16;
                // cg = h*128 + l*32 + p*2 + xy
                const int xy = cg & 1, p = (cg >> 1) & 15, l = (cg >> 5) & 3;
                const float lam = (float)p * (1.0f / 15.0f);
                const float l2 = lam * lam, l3 = l2 * lam;
                const float rW = (l == 0) ? 0.015625f : (l == 1) ? 0.03125f
                                : (l == 2) ? 0.0625f : 0.125f;
                const float bv = bias[cg];
#pragma unroll
                for (int mi = 0; mi < 4; ++mi) {
                    const int r0 = row0 + wr * 64 + mi * 16 + quad * 4;
#pragma unroll
                    for (int rr = 0; rr < 4; ++rr) {
                        const int r = r0 + rr;
                        const float4 rp = *(const float4*)(refp + (size_t)r * 8 + xy * 4);
                        const float poly = rp.x * l3 + rp.y * l2 + rp.z * lam + rp.w;
                        C[(size_t)r * 1024 + cg] = poly + (acc[mi][ni][rr] + bv) * rW;
                    }
                }
            }
        } else {
            // fused softmax over each (row, head)'s 64 logits
            const int cabase = col0 - 1024 + wc * 64;   // multiple of 64
            float bv[4];
#pragma unroll
            for (int ni = 0; ni < 4; ++ni) bv[ni] = bias2[cabase + ni * 16 + l16];
#pragma unroll
            for (int mi = 0; mi < 4; ++mi) {
                const int r0 = row0 + wr * 64 + mi * 16 + quad * 4;
#pragma unroll
                for (int rr = 0; rr < 4; ++rr) {
                    float v0 = acc[mi][0][rr] + bv[0];
                    float v1 = acc[mi][1][rr] + bv[1];
                    float v2 = acc[mi][2][rr] + bv[2];
                    float v3 = acc[mi][3][rr] + bv[3];
                    float mx = fmaxf(fmaxf(v0, v1), fmaxf(v2, v3));
#pragma unroll
                    for (int mk = 1; mk < 16; mk <<= 1) mx = fmaxf(mx, __shfl_xor(mx, mk));
                    v0 = __expf(v0 - mx); v1 = __expf(v1 - mx);
                    v2 = __expf(v2 - mx); v3 = __expf(v3 - mx);
                    float s = v0 + v1 + v2 + v3;
#pragma unroll
                    for (int mk = 1; mk < 16; mk <<= 1) s += __shfl_xor(s, mk);
                    const float inv = 1.0f / s;
                    const size_t rb = (size_t)(r0 + rr) * 512 + cabase + l16;
                    C2[rb]      = v0 * inv;
                    C2[rb + 16] = v1 * inv;
                    C2[rb + 32] = v2 * inv;
                    C2[rb + 48] = v3 * inv;
                }
            }
        }
    }
}

// One launch: v-projection (blocks 0..339) + fused offsets/attn GEMM (340..723).
__global__ __launch_bounds__(256, 2) void gemm_fused(const unsigned short* __restrict__ val_h,
                                                     const unsigned short* __restrict__ qry_h,
                                                     const unsigned short* __restrict__ Wt,
                                                     const float* __restrict__ b_value,
                                                     const float* __restrict__ b_off,
                                                     const float* __restrict__ b_attn,
                                                     const float* __restrict__ refp,
                                                     unsigned short* __restrict__ v_pad,
                                                     float* __restrict__ loc_out,
                                                     float* __restrict__ attn_out) {
    const int b = blockIdx.x;
    if (b < 340) {
        gemm_nolds<2>(val_h, Wt, b_value, nullptr, nullptr,
                      v_pad, nullptr, 256, b & 1, b >> 1);
    } else {
        const int b2 = b - 340;
        gemm_nolds<1>(qry_h, Wt + (size_t)256 * KDIM, b_off, b_attn, refp,
                      loc_out, attn_out, 1536, b2 % 12, b2 / 12);
    }
}

// out-projection: fp32 out = interm(f16, fragment-major) @ W_out^T + b_out
__global__ __launch_bounds__(256, 2) void gemm_outp(const unsigned short* __restrict__ interm,
                                                    const unsigned short* __restrict__ Wt_out,
                                                    const float* __restrict__ b_out,
                                                    float* __restrict__ out) {
    gemm_nolds<0>(interm, Wt_out, b_out, nullptr, nullptr,
                  out, nullptr, 256, blockIdx.x & 1, blockIdx.x >> 1);
}

// ---------------- bilinear sampling + attention weighting (padded f16 v) ---------
// 16 lanes per (b,q,h): lane = (lvl 0..3) x (channel-octet 0..3); each lane
// loads 8 f16 channels (16B) per corner. Zero-padded border: no masks/clamps.
// Packed f16 accumulate: per corner one v_cvt_pkrtz weight pack + 4
// v_pk_fma_f16 replaces 8 bf16 shifts + 8 f32 fma (~45% VALU cut). Per-level
// accumulation in f16 (16 adds, softmax weights <=1 -> error ~1e-3), cross-level
// reduce in fp32. ANTI-SPILL (R4): point loop NOT unrolled.
__global__ __launch_bounds__(256, 4) void sample_kernel(const unsigned short* __restrict__ v,
                                                        const float* __restrict__ loc,
                                                        const float* __restrict__ attn,
                                                        unsigned short* __restrict__ interm) {
    const int t = threadIdx.x;
    const int g = blockIdx.x * 16 + (t >> 4);   // (b*1024+q)*8 + h
    const int l16i = t & 15;
    const int lvl = l16i >> 2;                  // level 0..3
    const int cq  = l16i & 3;                   // channel octet (8 f16)
    const int h = g & 7, bq = g >> 3, b = bq >> 10;

    const int Wd = 64 >> lvl;
    const float Wf = (float)Wd;
    const int W2 = Wd + 2;
    const int rowoff = W2 * EMB;
    const int pb = (lvl == 0) ? 0 : (lvl == 1) ? 4356 : (lvl == 2) ? 5512 : 5836;

    const float* lp = loc  + (size_t)g * 128 + lvl * 32;   // this level's 16 pts
    const float* ap = attn + (size_t)g * 64  + lvl * 16;
    const unsigned short* vl = v + ((size_t)b * LVP + pb) * EMB + h * HD + cq * 8;

    h2 acc2[4] = {};

    auto cadd = [&](const uint4 q, h2 w) {
        acc2[0] += __builtin_bit_cast(h2, q.x) * w;   // v_pk_fma_f16
        acc2[1] += __builtin_bit_cast(h2, q.y) * w;
        acc2[2] += __builtin_bit_cast(h2, q.z) * w;
        acc2[3] += __builtin_bit_cast(h2, q.w) * w;
    };

    auto point = [&](float lx, float ly, float wt) {
        const float x = fmaf(lx, Wf, -0.5f);
        const float y = fmaf(ly, Wf, -0.5f);
        const float xc = fminf(fmaxf(x, -1.0f), Wf);
        const float yc = fminf(fmaxf(y, -1.0f), Wf);
        const float x0f = fminf(floorf(xc), Wf - 1.0f);
        const float y0f = fminf(floorf(yc), Wf - 1.0f);
        const float wx = xc - x0f, wy = yc - y0f;
        const float iwx = 1.0f - wx, iwy = 1.0f - wy;
        const int px = (int)x0f + 1;          // [0, W]
        const int py = (int)y0f + 1;          // [0, W]
        const int base = (py * W2 + px) * EMB;
        const float w00 = iwx * iwy * wt, w10 = wx * iwy * wt;
        const float w01 = iwx * wy * wt,  w11 = wx * wy * wt;
        const uint4 g00 = *(const uint4*)(vl + base);
        const uint4 g10 = *(const uint4*)(vl + base + EMB);
        const uint4 g01 = *(const uint4*)(vl + base + rowoff);
        const uint4 g11 = *(const uint4*)(vl + base + rowoff + EMB);
        cadd(g00, pk2(w00));
        cadd(g10, pk2(w10));
        cadd(g01, pk2(w01));
        cadd(g11, pk2(w11));
    };

#pragma unroll 1
    for (int p4 = 0; p4 < 16; p4 += 4) {
        const float4 la = *(const float4*)(lp + 2 * p4);
        const float4 lb = *(const float4*)(lp + 2 * p4 + 4);
        const float4 wv = *(const float4*)(ap + p4);
        point(la.x, la.y, wv.x); point(la.z, la.w, wv.y);
        point(lb.x, lb.y, wv.z); point(lb.z, lb.w, wv.w);
    }

    float a[8];
#pragma unroll
    for (int k = 0; k < 4; ++k) {
        a[2 * k]     = (float)acc2[k][0];
        a[2 * k + 1] = (float)acc2[k][1];
    }
    // reduce across the 4 level-quads (lane bits 2,3) in fp32
#pragma unroll
    for (int m = 4; m <= 8; m <<= 1)
#pragma unroll
        for (int k = 0; k < 8; ++k) a[k] += __shfl_xor(a[k], m);

    if (lvl == 0) {
        unsigned short o[8];
#pragma unroll
        for (int k = 0; k < 8; ++k) o[k] = f2h(a[k]);
        // fragment-major interm: row = bq, k = h*32 + cq*8
        const size_t off = ((size_t)(bq >> 4) * 8 + h) * 512
                         + ((bq & 15) + 16 * cq) * 8;
        *(uint4*)(interm + off) = *(const uint4*)o;
    }
}

// ---------------- host launch ----------------------------------------------------
extern "C" void kernel_launch(void* const* d_in, const int* in_sizes, int n_in,
                              void* d_out, int out_size, void* d_ws, size_t ws_size,
                              hipStream_t stream) {
    const float* query   = (const float*)d_in[0];
    const float* refp    = (const float*)d_in[1];
    const float* value   = (const float*)d_in[2];
    const float* W_value = (const float*)d_in[3];
    const float* b_value = (const float*)d_in[4];
    const float* W_off   = (const float*)d_in[5];
    const float* b_off   = (const float*)d_in[6];
    const float* W_attn  = (const float*)d_in[7];
    const float* b_attn  = (const float*)d_in[8];
    const float* W_out   = (const float*)d_in[9];
    const float* b_out   = (const float*)d_in[10];

    float* out      = (float*)d_out;            // [4,1024,256]
    float* loc_out  = out + 1048576;            // [4,1024,8,4,16,2]
    float* attn_out = out + 5242880;            // [4,1024,8,4,16]

    // workspace layout (26,443,776 B):
    //   [0, 12156928)           v_pad   (padded f16 v-projection)
    //   [12156928, 23298048)    val_h   (launches 1-2)  ALIASED WITH interm (3-4)
    //   [23298048, 25395200)    qry_h
    //   [25395200, 26443776)    Wt (fragment-major, 2048 rows x 256)
    char* ws = (char*)d_ws;
    unsigned short* v_pad  = (unsigned short*)ws;
    unsigned short* val_h  = (unsigned short*)(ws + 12156928);
    unsigned short* interm = (unsigned short*)(ws + 12156928);    // alias
    unsigned short* qry_h  = (unsigned short*)(ws + 23298048);
    unsigned short* Wt_all = (unsigned short*)(ws + 25395200);

    const dim3 blk(256);

    // weights -> fragment-major f16; value/query -> fragment-major f16; pad borders
    prep<<<1164, blk, 0, stream>>>(W_value, W_off, W_attn, W_out, value, query,
                                   Wt_all, val_h, qry_h, v_pad);

    // v-projection into padded layout (340 blocks) + fused offsets/attn GEMM (384)
    gemm_fused<<<724, blk, 0, stream>>>(val_h, qry_h, Wt_all, b_value, b_off,
                                        b_attn, refp, v_pad, loc_out, attn_out);

    // bilinear gather + attention weighting -> interm (fragment-major, overwrites val_h)
    sample_kernel<<<(BS * LQ * NH) / 16, blk, 0, stream>>>(v_pad, loc_out, attn_out, interm);

    // output = interm @ W_out^T + b_out
    gemm_outp<<<64, blk, 0, stream>>>(interm, Wt_all + (size_t)1792 * KDIM, b_out, out);
}